// Round 9
// baseline (2653.144 us; speedup 1.0000x reference)
//
#include <hip/hip_runtime.h>
#include <math.h>

#define NPTS 2048
#define NB 8
#define BN 16384   // NB*NPTS
#define KNN 16

// ---------------- fused sq + prep: blockIdx < BN/256 -> sq; else -> Wcat/bcat ----------
__global__ __launch_bounds__(256) void sqprep_kernel(const float* __restrict__ X,
                                                     float* __restrict__ SQ,
                                                     const float* __restrict__ W1,
                                                     const float* __restrict__ b1,
                                                     float* __restrict__ Wcat,
                                                     float* __restrict__ bcat,
                                                     int din, int d2) {
    const int bid = blockIdx.x;
    if (bid < BN / 256) {
        int g = bid * 256 + threadIdx.x;
        const float* row = X + (size_t)g * din;
        float s = 0.f;
        for (int d = 0; d < din; ++d) s = fmaf(row[d], row[d], s);
        SQ[g] = s;
    } else {
        int n4 = 2 * d2;
        int total = din * n4;
        int i = (bid - BN / 256) * 256 + threadIdx.x;
        if (i < total) {
            int d = i / n4, c = i - d * n4;
            float v;
            if (c < d2) v = W1[d * d2 + c] - W1[(din + d) * d2 + c];
            else        v = W1[(din + d) * d2 + (c - d2)];
            Wcat[i] = v;
        }
        if (i < n4) bcat[i] = (i < d2) ? b1[i] : 0.f;
    }
}

// ---------------- gram: DT[i][j] = (sq_i + sq_j) - 2*dot(x_i,x_j), per batch ----------
// 128x128 tile, 8x8/thread, BK=32 (DIN%32==0) else BK=16 scalar path (DIN=3).
// NO register prefetch (R7: spills). At fp32 LDS-BW structural plateau (~100 TF).
template <int DIN>
__global__ __launch_bounds__(256) void gram_kernel(const float* __restrict__ X,
                                                   const float* __restrict__ SQ,
                                                   float* __restrict__ DT) {
    __shared__ float As[32][132];
    __shared__ float Bs[32][132];
    const int t = threadIdx.x;
    const int tx = t & 15, ty = t >> 4;
    const int i0 = blockIdx.x * 128;
    const int j0 = blockIdx.y * 128;
    const int z = blockIdx.z;
    const float* Xb = X + (size_t)z * NPTS * DIN;
    const float* SQb = SQ + (size_t)z * NPTS;
    float* DTb = DT + (size_t)z * NPTS * NPTS;

    const int e = t & 127;

    float acc[8][8];
    #pragma unroll
    for (int i = 0; i < 8; ++i)
        #pragma unroll
        for (int j = 0; j < 8; ++j) acc[i][j] = 0.f;

    if constexpr (DIN % 32 == 0) {
        const int rh = (t >> 7) * 16;   // 0 or 16
        const float* Ar = Xb + (size_t)(i0 + e) * DIN;
        const float* Br = Xb + (size_t)(j0 + e) * DIN;
        for (int k0 = 0; k0 < DIN; k0 += 32) {
            #pragma unroll
            for (int h = 0; h < 4; ++h) {
                float4 a = *(const float4*)(Ar + k0 + rh + h * 4);
                float4 b = *(const float4*)(Br + k0 + rh + h * 4);
                As[rh + h * 4 + 0][e] = a.x; As[rh + h * 4 + 1][e] = a.y;
                As[rh + h * 4 + 2][e] = a.z; As[rh + h * 4 + 3][e] = a.w;
                Bs[rh + h * 4 + 0][e] = b.x; Bs[rh + h * 4 + 1][e] = b.y;
                Bs[rh + h * 4 + 2][e] = b.z; Bs[rh + h * 4 + 3][e] = b.w;
            }
            __syncthreads();
            #pragma unroll
            for (int r = 0; r < 32; ++r) {
                float4 a0 = *(const float4*)&As[r][ty * 4];
                float4 a1 = *(const float4*)&As[r][64 + ty * 4];
                float4 b0 = *(const float4*)&Bs[r][tx * 4];
                float4 b1 = *(const float4*)&Bs[r][64 + tx * 4];
                float av[8] = {a0.x, a0.y, a0.z, a0.w, a1.x, a1.y, a1.z, a1.w};
                float bv[8] = {b0.x, b0.y, b0.z, b0.w, b1.x, b1.y, b1.z, b1.w};
                #pragma unroll
                for (int i = 0; i < 8; ++i)
                    #pragma unroll
                    for (int j = 0; j < 8; ++j)
                        acc[i][j] = fmaf(av[i], bv[j], acc[i][j]);
            }
            __syncthreads();
        }
    } else {
        const int rh = (t >> 7) * 8;
        #pragma unroll
        for (int i = 0; i < 8; ++i) {
            int k = rh + i;
            As[rh + i][e] = (k < DIN) ? Xb[(size_t)(i0 + e) * DIN + k] : 0.f;
            Bs[rh + i][e] = (k < DIN) ? Xb[(size_t)(j0 + e) * DIN + k] : 0.f;
        }
        __syncthreads();
        #pragma unroll
        for (int r = 0; r < 16; ++r) {
            float4 a0 = *(const float4*)&As[r][ty * 4];
            float4 a1 = *(const float4*)&As[r][64 + ty * 4];
            float4 b0 = *(const float4*)&Bs[r][tx * 4];
            float4 b1 = *(const float4*)&Bs[r][64 + tx * 4];
            float av[8] = {a0.x, a0.y, a0.z, a0.w, a1.x, a1.y, a1.z, a1.w};
            float bv[8] = {b0.x, b0.y, b0.z, b0.w, b1.x, b1.y, b1.z, b1.w};
            #pragma unroll
            for (int i = 0; i < 8; ++i)
                #pragma unroll
                for (int j = 0; j < 8; ++j)
                    acc[i][j] = fmaf(av[i], bv[j], acc[i][j]);
        }
        __syncthreads();
    }

    float sqi[8], sqj[8];
    #pragma unroll
    for (int i = 0; i < 8; ++i) {
        int ro = (i < 4) ? (ty * 4 + i) : (64 + ty * 4 + (i - 4));
        sqi[i] = SQb[i0 + ro];
    }
    #pragma unroll
    for (int j = 0; j < 8; ++j) {
        int co = (j < 4) ? (tx * 4 + j) : (64 + tx * 4 + (j - 4));
        sqj[j] = SQb[j0 + co];
    }
    #pragma unroll
    for (int i = 0; i < 8; ++i) {
        int ro = (i < 4) ? (ty * 4 + i) : (64 + ty * 4 + (i - 4));
        float* out = DTb + (size_t)(i0 + ro) * NPTS + j0;
        float4 o0, o1;
        o0.x = (sqi[i] + sqj[0]) - 2.f * acc[i][0];
        o0.y = (sqi[i] + sqj[1]) - 2.f * acc[i][1];
        o0.z = (sqi[i] + sqj[2]) - 2.f * acc[i][2];
        o0.w = (sqi[i] + sqj[3]) - 2.f * acc[i][3];
        o1.x = (sqi[i] + sqj[4]) - 2.f * acc[i][4];
        o1.y = (sqi[i] + sqj[5]) - 2.f * acc[i][5];
        o1.z = (sqi[i] + sqj[6]) - 2.f * acc[i][6];
        o1.w = (sqi[i] + sqj[7]) - 2.f * acc[i][7];
        *(float4*)(out + tx * 4) = o0;
        *(float4*)(out + 64 + tx * 4) = o1;
    }
}

// ---------------- knn select: tournament (8 groups of 4) per lane ----------------
// Comparator-equivalent to full ascending-slot scan: within-group ascending strict <,
// group merge ascending strict < -> smallest val, smallest index on ties.
__global__ __launch_bounds__(256) void knn_select_kernel(const float* __restrict__ DT,
                                                         int* __restrict__ IDX, int qoff) {
    const int t = threadIdx.x;
    const int w = t >> 6, lane = t & 63;
    const int q = blockIdx.x * 4 + w;       // half-local query
    const float* dq = DT + (size_t)q * NPTS;
    const int l4 = lane << 2;

    float vals[32];
    #pragma unroll
    for (int s = 0; s < 8; ++s) {
        float4 v = *(const float4*)(dq + s * 256 + l4);
        vals[s * 4 + 0] = v.x; vals[s * 4 + 1] = v.y;
        vals[s * 4 + 2] = v.z; vals[s * 4 + 3] = v.w;
    }
    unsigned rm = 0;
    float gmin[8]; int gslot[8];
    #pragma unroll
    for (int g = 0; g < 8; ++g) {
        float m = vals[4 * g]; int sl = 4 * g;
        #pragma unroll
        for (int i = 1; i < 4; ++i)
            if (vals[4 * g + i] < m) { m = vals[4 * g + i]; sl = 4 * g + i; }
        gmin[g] = m; gslot[g] = sl;
    }

    for (int rep = 0; rep < KNN; ++rep) {
        float best = gmin[0]; int bslot = gslot[0];
        #pragma unroll
        for (int g = 1; g < 8; ++g)
            if (gmin[g] < best) { best = gmin[g]; bslot = gslot[g]; }
        int bj = (bslot < 32) ? ((bslot >> 2) * 256 + l4 + (bslot & 3)) : NPTS;
        float gb = best; int gj = bj;
        #pragma unroll
        for (int off = 1; off < 64; off <<= 1) {
            float ov = __shfl_xor(gb, off);
            int oj = __shfl_xor(gj, off);
            if (ov < gb || (ov == gb && oj < gj)) { gb = ov; gj = oj; }
        }
        if (lane == 0) IDX[(size_t)(qoff + q) * KNN + rep] = gj;
        if (((gj >> 2) & 63) == lane) {      // owner: remove + rescan its group only
            int slot = ((gj >> 8) << 2) | (gj & 3);
            rm |= (1u << slot);
            int g = slot >> 2;
            float m = INFINITY; int sl = 64;
            #pragma unroll
            for (int i = 0; i < 4; ++i) {
                int s2 = 4 * g + i;
                if (!(rm & (1u << s2)) && vals[s2] < m) { m = vals[s2]; sl = s2; }
            }
            gmin[g] = m; gslot[g] = sl;
        }
    }
}

// ---------------- gemm big: C[M,N] = A[M,K]@B[K,N] + bias, 128x128, BK=32, plain -----
template <int KK, int NN>
__global__ __launch_bounds__(256) void gemm_big_kernel(const float* __restrict__ A,
                                                       const float* __restrict__ B,
                                                       const float* __restrict__ bias,
                                                       float* __restrict__ C) {
    __shared__ float As[32][132];
    __shared__ float Bs[32][132];
    const int t = threadIdx.x;
    const int tx = t & 15, ty = t >> 4;
    const int m0 = blockIdx.x * 128;
    const int c0 = blockIdx.y * 128;

    float acc[8][8];
    #pragma unroll
    for (int i = 0; i < 8; ++i)
        #pragma unroll
        for (int j = 0; j < 8; ++j) acc[i][j] = 0.f;

    const int e = t & 127;
    const int rh = (t >> 7) * 16;   // 0 or 16
    const float* Ar = A + (size_t)(m0 + e) * KK + rh;
    const int br = t & 31;
    const int bc = (t >> 5) * 16;
    const float* Wbase = B + (size_t)br * NN + c0 + bc;

    for (int k0 = 0; k0 < KK; k0 += 32) {
        #pragma unroll
        for (int h = 0; h < 4; ++h) {
            float4 a = *(const float4*)(Ar + k0 + h * 4);
            As[rh + h * 4 + 0][e] = a.x; As[rh + h * 4 + 1][e] = a.y;
            As[rh + h * 4 + 2][e] = a.z; As[rh + h * 4 + 3][e] = a.w;
            *(float4*)&Bs[br][bc + h * 4] = *(const float4*)(Wbase + (size_t)k0 * NN + h * 4);
        }
        __syncthreads();
        #pragma unroll
        for (int r = 0; r < 32; ++r) {
            float4 a0 = *(const float4*)&As[r][ty * 4];
            float4 a1 = *(const float4*)&As[r][64 + ty * 4];
            float4 b0 = *(const float4*)&Bs[r][tx * 4];
            float4 b1 = *(const float4*)&Bs[r][64 + tx * 4];
            float av[8] = {a0.x, a0.y, a0.z, a0.w, a1.x, a1.y, a1.z, a1.w};
            float bv[8] = {b0.x, b0.y, b0.z, b0.w, b1.x, b1.y, b1.z, b1.w};
            #pragma unroll
            for (int i = 0; i < 8; ++i)
                #pragma unroll
                for (int j = 0; j < 8; ++j)
                    acc[i][j] = fmaf(av[i], bv[j], acc[i][j]);
        }
        __syncthreads();
    }

    float bvv[8];
    #pragma unroll
    for (int j = 0; j < 8; ++j) {
        int co = (j < 4) ? (tx * 4 + j) : (64 + tx * 4 + (j - 4));
        bvv[j] = bias[c0 + co];
    }
    #pragma unroll
    for (int i = 0; i < 8; ++i) {
        int ro = (i < 4) ? (ty * 4 + i) : (64 + ty * 4 + (i - 4));
        float* out = C + (size_t)(m0 + ro) * NN + c0;
        float4 o0, o1;
        o0.x = acc[i][0] + bvv[0]; o0.y = acc[i][1] + bvv[1];
        o0.z = acc[i][2] + bvv[2]; o0.w = acc[i][3] + bvv[3];
        o1.x = acc[i][4] + bvv[4]; o1.y = acc[i][5] + bvv[5];
        o1.z = acc[i][6] + bvv[6]; o1.w = acc[i][7] + bvv[7];
        *(float4*)(out + tx * 4) = o0;
        *(float4*)(out + 64 + tx * 4) = o1;
    }
}

// ---------------- generic tiled GEMM (fallback, 64x64): C = A@B + bias ----------------
template <int KK, int NN>
__global__ __launch_bounds__(256) void gemm_pq_kernel(const float* __restrict__ A,
                                                      const float* __restrict__ B,
                                                      const float* __restrict__ bias,
                                                      float* __restrict__ C) {
    __shared__ float As[16][68];
    __shared__ float Bs[16][64];
    const int t = threadIdx.x;
    const int tx = t & 15, ty = t >> 4;
    const int m0 = blockIdx.x * 64;
    const int c0 = blockIdx.y * 64;
    float acc[4][4];
    #pragma unroll
    for (int i = 0; i < 4; ++i)
        #pragma unroll
        for (int j = 0; j < 4; ++j) acc[i][j] = 0.f;

    constexpr int KCH = (KK + 15) / 16;
    for (int kc = 0; kc < KCH; ++kc) {
        const int k0 = kc * 16;
        {
            int m = t & 63;
            int r4 = (t >> 6) * 4;
            if constexpr (KK % 16 == 0) {
                float4 v = *(const float4*)(A + (size_t)(m0 + m) * KK + k0 + r4);
                As[r4 + 0][m] = v.x; As[r4 + 1][m] = v.y;
                As[r4 + 2][m] = v.z; As[r4 + 3][m] = v.w;
            } else {
                #pragma unroll
                for (int i = 0; i < 4; ++i) {
                    int r = r4 + i;
                    As[r][m] = (k0 + r < KK) ? A[(size_t)(m0 + m) * KK + k0 + r] : 0.f;
                }
            }
        }
        {
            int r = t >> 4;
            int c = (t & 15) * 4;
            float4 v = make_float4(0.f, 0.f, 0.f, 0.f);
            if (k0 + r < KK) v = *(const float4*)(B + (size_t)(k0 + r) * NN + c0 + c);
            *(float4*)&Bs[r][c] = v;
        }
        __syncthreads();
        #pragma unroll
        for (int r = 0; r < 16; ++r) {
            float4 a4 = *(const float4*)&As[r][ty * 4];
            float4 b4 = *(const float4*)&Bs[r][tx * 4];
            float av[4] = {a4.x, a4.y, a4.z, a4.w};
            float bv[4] = {b4.x, b4.y, b4.z, b4.w};
            #pragma unroll
            for (int i = 0; i < 4; ++i)
                #pragma unroll
                for (int j = 0; j < 4; ++j)
                    acc[i][j] = fmaf(av[i], bv[j], acc[i][j]);
        }
        __syncthreads();
    }
    float4 bv4 = *(const float4*)(bias + c0 + tx * 4);
    float bv[4] = {bv4.x, bv4.y, bv4.z, bv4.w};
    #pragma unroll
    for (int i = 0; i < 4; ++i) {
        float4 o;
        o.x = acc[i][0] + bv[0];
        o.y = acc[i][1] + bv[1];
        o.z = acc[i][2] + bv[2];
        o.w = acc[i][3] + bv[3];
        *(float4*)(C + (size_t)(m0 + ty * 4 + i) * NN + c0 + tx * 4) = o;
    }
}

// ---------------- edge mid (DOUT<=64): 128 edges x 64 cols, 8x4/thread, BK=32 --------
// Guarded for DOUT in {16,32,64}. Per-(edge,col) fma chain ascending k; 4+4+4+4 mean.
template <int D2, int DOUT>
__global__ __launch_bounds__(256) void edge_mid_kernel(const float* __restrict__ PQ,
                                                       const int* __restrict__ IDX,
                                                       const float* __restrict__ W2,
                                                       const float* __restrict__ b2,
                                                       float* __restrict__ Xn) {
    constexpr int N4 = 2 * D2;
    __shared__ float As[32][132];
    __shared__ float Bs[32][68];
    __shared__ int gjs[128];
    const int t = threadIdx.x;
    const int tx = t & 15, ty = t >> 4;
    const int nb8 = blockIdx.x * 8;

    if (t < 128) {
        int node = nb8 + (t >> 4);
        int bstart = (node / NPTS) * NPTS;
        gjs[t] = bstart + IDX[(size_t)node * KNN + (t & 15)];
    }
    __syncthreads();

    float acc[8][4];
    #pragma unroll
    for (int i = 0; i < 8; ++i)
        #pragma unroll
        for (int j = 0; j < 4; ++j) acc[i][j] = 0.f;

    const int e = t & 127;
    const int rh = (t >> 7) * 16;   // 0 or 16
    const int gi = nb8 + (e >> 4);
    const int gj = gjs[e];
    const float* Prow = PQ + (size_t)gi * N4;
    const float* Qrow = PQ + (size_t)gj * N4 + D2;
    const int br = t & 31;
    const int bc = (t >> 5) * 8;
    const float* Wbase = W2 + (size_t)br * DOUT + bc;

    for (int k0 = 0; k0 < D2; k0 += 32) {
        if (k0 + rh < D2) {   // D2==32 has only rh==0 rows valid for upper half? no: rh<32 always valid since D2>=32
            #pragma unroll
            for (int h = 0; h < 4; ++h) {
                float4 p = *(const float4*)(Prow + k0 + rh + h * 4);
                float4 q = *(const float4*)(Qrow + k0 + rh + h * 4);
                As[rh + h * 4 + 0][e] = fmaxf(p.x + q.x, 0.f);
                As[rh + h * 4 + 1][e] = fmaxf(p.y + q.y, 0.f);
                As[rh + h * 4 + 2][e] = fmaxf(p.z + q.z, 0.f);
                As[rh + h * 4 + 3][e] = fmaxf(p.w + q.w, 0.f);
            }
        }
        if (bc < DOUT) {
            const float* wp = Wbase + (size_t)k0 * DOUT;
            *(float4*)&Bs[br][bc] = *(const float4*)(wp);
            *(float4*)&Bs[br][bc + 4] = *(const float4*)(wp + 4);
        }
        __syncthreads();
        #pragma unroll
        for (int r = 0; r < 32; ++r) {
            float4 a0 = *(const float4*)&As[r][ty * 4];
            float4 a1 = *(const float4*)&As[r][64 + ty * 4];
            float4 b0 = *(const float4*)&Bs[r][tx * 4];
            float av[8] = {a0.x, a0.y, a0.z, a0.w, a1.x, a1.y, a1.z, a1.w};
            float bv[4] = {b0.x, b0.y, b0.z, b0.w};
            #pragma unroll
            for (int i = 0; i < 8; ++i)
                #pragma unroll
                for (int j = 0; j < 4; ++j)
                    acc[i][j] = fmaf(av[i], bv[j], acc[i][j]);
        }
        __syncthreads();
    }

    #pragma unroll
    for (int j = 0; j < 4; ++j) {
        int cl = tx * 4 + j;
        float bb = (cl < DOUT) ? b2[cl] : 0.f;
        float s0 = 0.f, s1 = 0.f;
        #pragma unroll
        for (int i = 0; i < 4; ++i) {
            s0 += fmaxf(acc[i][j] + bb, 0.f);
            s1 += fmaxf(acc[4 + i][j] + bb, 0.f);
        }
        As[ty][cl] = s0;       // nodes 0..3 partials
        Bs[ty][cl] = s1;       // nodes 4..7 partials
    }
    __syncthreads();
    if (t < 128) {
        int node = t >> 4;             // 0..7
        int colb = (t & 15) * 4;
        if (colb < DOUT) {
            int tg = (node & 3) * 4;
            float v0, v1, v2, v3;
            if (node < 4) {
                v0 = As[tg + 0][colb + 0] + As[tg + 1][colb + 0] + As[tg + 2][colb + 0] + As[tg + 3][colb + 0];
                v1 = As[tg + 0][colb + 1] + As[tg + 1][colb + 1] + As[tg + 2][colb + 1] + As[tg + 3][colb + 1];
                v2 = As[tg + 0][colb + 2] + As[tg + 1][colb + 2] + As[tg + 2][colb + 2] + As[tg + 3][colb + 2];
                v3 = As[tg + 0][colb + 3] + As[tg + 1][colb + 3] + As[tg + 2][colb + 3] + As[tg + 3][colb + 3];
            } else {
                v0 = Bs[tg + 0][colb + 0] + Bs[tg + 1][colb + 0] + Bs[tg + 2][colb + 0] + Bs[tg + 3][colb + 0];
                v1 = Bs[tg + 0][colb + 1] + Bs[tg + 1][colb + 1] + Bs[tg + 2][colb + 1] + Bs[tg + 3][colb + 1];
                v2 = Bs[tg + 0][colb + 2] + Bs[tg + 1][colb + 2] + Bs[tg + 2][colb + 2] + Bs[tg + 3][colb + 2];
                v3 = Bs[tg + 0][colb + 3] + Bs[tg + 1][colb + 3] + Bs[tg + 2][colb + 3] + Bs[tg + 3][colb + 3];
            }
            float4 o;
            o.x = v0 * (1.f / 16.f); o.y = v1 * (1.f / 16.f);
            o.z = v2 * (1.f / 16.f); o.w = v3 * (1.f / 16.f);
            *(float4*)(Xn + (size_t)(nb8 + node) * DOUT + colb) = o;
        }
    }
}

// ---------------- edge big (DOUT>=128): 128x128, 8x8/thread, BK=32, plain ------------
template <int D2, int DOUT>
__global__ __launch_bounds__(256) void edge_big_kernel(const float* __restrict__ PQ,
                                                       const int* __restrict__ IDX,
                                                       const float* __restrict__ W2,
                                                       const float* __restrict__ b2,
                                                       float* __restrict__ Xn) {
    constexpr int N4 = 2 * D2;
    __shared__ float As[32][132];
    __shared__ float Bs[32][132];
    __shared__ int gjs[128];
    const int t = threadIdx.x;
    const int tx = t & 15, ty = t >> 4;
    const int nb8 = blockIdx.x * 8;
    const int c0 = blockIdx.y * 128;

    if (t < 128) {
        int node = nb8 + (t >> 4);
        int bstart = (node / NPTS) * NPTS;
        gjs[t] = bstart + IDX[(size_t)node * KNN + (t & 15)];
    }
    __syncthreads();

    float acc[8][8];
    #pragma unroll
    for (int i = 0; i < 8; ++i)
        #pragma unroll
        for (int j = 0; j < 8; ++j) acc[i][j] = 0.f;

    const int e = t & 127;
    const int rh = (t >> 7) * 16;   // 0 or 16
    const int gi = nb8 + (e >> 4);
    const int gj = gjs[e];
    const float* Prow = PQ + (size_t)gi * N4;
    const float* Qrow = PQ + (size_t)gj * N4 + D2;
    const int br = t & 31;
    const int bc = (t >> 5) * 16;
    const float* Wbase = W2 + (size_t)br * DOUT + c0 + bc;

    for (int k0 = 0; k0 < D2; k0 += 32) {
        #pragma unroll
        for (int h = 0; h < 4; ++h) {
            float4 p = *(const float4*)(Prow + k0 + rh + h * 4);
            float4 q = *(const float4*)(Qrow + k0 + rh + h * 4);
            As[rh + h * 4 + 0][e] = fmaxf(p.x + q.x, 0.f);
            As[rh + h * 4 + 1][e] = fmaxf(p.y + q.y, 0.f);
            As[rh + h * 4 + 2][e] = fmaxf(p.z + q.z, 0.f);
            As[rh + h * 4 + 3][e] = fmaxf(p.w + q.w, 0.f);
        }
        {
            const float* wp = Wbase + (size_t)k0 * DOUT;
            #pragma unroll
            for (int h = 0; h < 4; ++h)
                *(float4*)&Bs[br][bc + h * 4] = *(const float4*)(wp + h * 4);
        }
        __syncthreads();
        #pragma unroll
        for (int r = 0; r < 32; ++r) {
            float4 a0 = *(const float4*)&As[r][ty * 4];
            float4 a1 = *(const float4*)&As[r][64 + ty * 4];
            float4 b0 = *(const float4*)&Bs[r][tx * 4];
            float4 b1 = *(const float4*)&Bs[r][64 + tx * 4];
            float av[8] = {a0.x, a0.y, a0.z, a0.w, a1.x, a1.y, a1.z, a1.w};
            float bv[8] = {b0.x, b0.y, b0.z, b0.w, b1.x, b1.y, b1.z, b1.w};
            #pragma unroll
            for (int i = 0; i < 8; ++i)
                #pragma unroll
                for (int j = 0; j < 8; ++j)
                    acc[i][j] = fmaf(av[i], bv[j], acc[i][j]);
        }
        __syncthreads();
    }

    #pragma unroll
    for (int j = 0; j < 8; ++j) {
        int cl = (j < 4) ? (tx * 4 + j) : (64 + tx * 4 + (j - 4));
        float bb = b2[c0 + cl];
        float s0 = 0.f, s1 = 0.f;
        #pragma unroll
        for (int i = 0; i < 4; ++i) {
            s0 += fmaxf(acc[i][j] + bb, 0.f);
            s1 += fmaxf(acc[4 + i][j] + bb, 0.f);
        }
        As[ty][cl] = s0;
        Bs[ty][cl] = s1;
    }
    __syncthreads();
    {
        int node = t >> 5;
        int colb = (t * 4) & 127;
        int tg = (node & 3) * 4;
        float4 o;
        float v0, v1, v2, v3;
        if (node < 4) {
            v0 = As[tg + 0][colb + 0] + As[tg + 1][colb + 0] + As[tg + 2][colb + 0] + As[tg + 3][colb + 0];
            v1 = As[tg + 0][colb + 1] + As[tg + 1][colb + 1] + As[tg + 2][colb + 1] + As[tg + 3][colb + 1];
            v2 = As[tg + 0][colb + 2] + As[tg + 1][colb + 2] + As[tg + 2][colb + 2] + As[tg + 3][colb + 2];
            v3 = As[tg + 0][colb + 3] + As[tg + 1][colb + 3] + As[tg + 2][colb + 3] + As[tg + 3][colb + 3];
        } else {
            v0 = Bs[tg + 0][colb + 0] + Bs[tg + 1][colb + 0] + Bs[tg + 2][colb + 0] + Bs[tg + 3][colb + 0];
            v1 = Bs[tg + 0][colb + 1] + Bs[tg + 1][colb + 1] + Bs[tg + 2][colb + 1] + Bs[tg + 3][colb + 1];
            v2 = Bs[tg + 0][colb + 2] + Bs[tg + 1][colb + 2] + Bs[tg + 2][colb + 2] + Bs[tg + 3][colb + 2];
            v3 = Bs[tg + 0][colb + 3] + Bs[tg + 1][colb + 3] + Bs[tg + 2][colb + 3] + Bs[tg + 3][colb + 3];
        }
        o.x = v0 * (1.f / 16.f); o.y = v1 * (1.f / 16.f);
        o.z = v2 * (1.f / 16.f); o.w = v3 * (1.f / 16.f);
        *(float4*)(Xn + (size_t)(nb8 + node) * DOUT + c0 + colb) = o;
    }
}

// ---------------- final: mean over nodes + 16x2 projection ----------------
__global__ __launch_bounds__(256) void final_kernel(const float* __restrict__ X,
                                                    const float* __restrict__ Wf,
                                                    const float* __restrict__ bfin,
                                                    float* __restrict__ out) {
    __shared__ float red[16][17];
    __shared__ float pool[16];
    const int b = blockIdx.x;
    const int t = threadIdx.x;
    const int c = t & 15, rg = t >> 4;
    float s = 0.f;
    for (int n = rg; n < NPTS; n += 16) s += X[(size_t)(b * NPTS + n) * 16 + c];
    red[rg][c] = s;
    __syncthreads();
    if (t < 16) {
        float tot = 0.f;
        #pragma unroll
        for (int i = 0; i < 16; ++i) tot += red[i][t];
        pool[t] = tot * (1.f / NPTS);
    }
    __syncthreads();
    if (t < 2) {
        float a = bfin[t];
        #pragma unroll
        for (int cc = 0; cc < 16; ++cc) a = fmaf(pool[cc], Wf[cc * 2 + t], a);
        out[b * 2 + t] = a;
    }
}

// ---------------- per-layer driver ----------------
template <int DIN, int DOUT>
static void run_layer(const float* Xin, float* Xout, float* PQ, float* SQ, int* IDX,
                      float* WCAT, float* BCAT,
                      const float* W1, const float* b1, const float* W2, const float* b2,
                      hipStream_t stream) {
    constexpr int D2 = 2 * DOUT;
    constexpr int N4 = 2 * D2;
    int prep_blocks = (DIN * N4 + 255) / 256;
    sqprep_kernel<<<BN / 256 + prep_blocks, 256, 0, stream>>>(Xin, SQ, W1, b1, WCAT, BCAT, DIN, D2);
    for (int h = 0; h < 2; ++h) {
        dim3 gg(16, 16, 4);
        gram_kernel<DIN><<<gg, 256, 0, stream>>>(Xin + (size_t)h * 4 * NPTS * DIN,
                                                 SQ + (size_t)h * 4 * NPTS, PQ);
        knn_select_kernel<<<2048, 256, 0, stream>>>(PQ, IDX, h * 8192);
    }
    if constexpr (N4 % 128 == 0 && DIN % 32 == 0) {
        dim3 g1(BN / 128, N4 / 128);
        gemm_big_kernel<DIN, N4><<<g1, 256, 0, stream>>>(Xin, WCAT, BCAT, PQ);
    } else {
        dim3 g1(BN / 64, N4 / 64);
        gemm_pq_kernel<DIN, N4><<<g1, 256, 0, stream>>>(Xin, WCAT, BCAT, PQ);
    }
    if constexpr (DOUT >= 128) {
        dim3 g2(BN / 8, DOUT / 128);
        edge_big_kernel<D2, DOUT><<<g2, 256, 0, stream>>>(PQ, IDX, W2, b2, Xout);
    } else {
        dim3 g2(BN / 8, 1);
        edge_mid_kernel<D2, DOUT><<<g2, 256, 0, stream>>>(PQ, IDX, W2, b2, Xout);
    }
}

extern "C" void kernel_launch(void* const* d_in, const int* in_sizes, int n_in,
                              void* d_out, int out_size, void* d_ws, size_t ws_size,
                              hipStream_t stream) {
    (void)in_sizes; (void)n_in; (void)out_size; (void)ws_size;
    const float* x = (const float*)d_in[0];
    const float* W1a[6]; const float* b1a[6]; const float* W2a[6]; const float* b2a[6];
    for (int l = 0; l < 6; ++l) {
        W1a[l] = (const float*)d_in[1 + 4 * l];
        b1a[l] = (const float*)d_in[2 + 4 * l];
        W2a[l] = (const float*)d_in[3 + 4 * l];
        b2a[l] = (const float*)d_in[4 + 4 * l];
    }
    const float* Wf = (const float*)d_in[25];
    const float* bfin = (const float*)d_in[26];

    float* ws = (float*)d_ws;
    float* X0   = ws;                                   // 16384*256
    float* X1   = X0 + (size_t)BN * 256;                // 16384*256
    float* PQ   = X1 + (size_t)BN * 256;                // 16384*1024 (also knn DT: 8192*2048)
    float* SQ   = PQ + (size_t)BN * 1024;               // 16384
    int*   IDX  = (int*)(SQ + BN);                      // 16384*16
    float* WCAT = (float*)(IDX + (size_t)BN * KNN);     // 131072
    float* BCAT = WCAT + 131072;                        // 1024

    run_layer<3,   32>(x,  X0, PQ, SQ, IDX, WCAT, BCAT, W1a[0], b1a[0], W2a[0], b2a[0], stream);
    run_layer<32, 128>(X0, X1, PQ, SQ, IDX, WCAT, BCAT, W1a[1], b1a[1], W2a[1], b2a[1], stream);
    run_layer<128,256>(X1, X0, PQ, SQ, IDX, WCAT, BCAT, W1a[2], b1a[2], W2a[2], b2a[2], stream);
    run_layer<256, 64>(X0, X1, PQ, SQ, IDX, WCAT, BCAT, W1a[3], b1a[3], W2a[3], b2a[3], stream);
    run_layer<64,  32>(X1, X0, PQ, SQ, IDX, WCAT, BCAT, W1a[4], b1a[4], W2a[4], b2a[4], stream);
    run_layer<32,  16>(X0, X1, PQ, SQ, IDX, WCAT, BCAT, W1a[5], b1a[5], W2a[5], b2a[5], stream);
    final_kernel<<<NB, 256, 0, stream>>>(X1, Wf, bfin, (float*)d_out);
}

// Round 10
// 2396.726 us; speedup vs baseline: 1.1070x; 1.1070x over previous
//
#include <hip/hip_runtime.h>
#include <math.h>

#define NPTS 2048
#define NB 8
#define BN 16384   // NB*NPTS
#define KNN 16

// ---------------- fused sq + prep: blockIdx < BN/256 -> sq; else -> Wcat/bcat ----------
__global__ __launch_bounds__(256) void sqprep_kernel(const float* __restrict__ X,
                                                     float* __restrict__ SQ,
                                                     const float* __restrict__ W1,
                                                     const float* __restrict__ b1,
                                                     float* __restrict__ Wcat,
                                                     float* __restrict__ bcat,
                                                     int din, int d2) {
    const int bid = blockIdx.x;
    if (bid < BN / 256) {
        int g = bid * 256 + threadIdx.x;
        const float* row = X + (size_t)g * din;
        float s = 0.f;
        for (int d = 0; d < din; ++d) s = fmaf(row[d], row[d], s);
        SQ[g] = s;
    } else {
        int n4 = 2 * d2;
        int total = din * n4;
        int i = (bid - BN / 256) * 256 + threadIdx.x;
        if (i < total) {
            int d = i / n4, c = i - d * n4;
            float v;
            if (c < d2) v = W1[d * d2 + c] - W1[(din + d) * d2 + c];
            else        v = W1[(din + d) * d2 + (c - d2)];
            Wcat[i] = v;
        }
        if (i < n4) bcat[i] = (i < d2) ? b1[i] : 0.f;
    }
}

// ---------------- gram (symmetric): triangular tile grid, mirror write ----------------
// 128x128 tile, 8x8/thread, BK=32 (DIN%32==0) else BK=16 (DIN=3). blockIdx.x in [0,136)
// decodes to (bi<=bj). dot's ascending-k fma chain is operand-swap bit-invariant and
// sq_i+sq_j commutes bit-exactly -> mirror block values identical to canonical compute.
template <int DIN>
__global__ __launch_bounds__(256) void gram_kernel(const float* __restrict__ X,
                                                   const float* __restrict__ SQ,
                                                   float* __restrict__ DT) {
    __shared__ float As[32][132];
    __shared__ float Bs[32][132];
    const int t = threadIdx.x;
    const int tx = t & 15, ty = t >> 4;
    int bid = blockIdx.x;
    int bi = 0;
    while (bid >= 16 - bi) { bid -= 16 - bi; ++bi; }
    const int bj = bi + bid;
    const int i0 = bi * 128;
    const int j0 = bj * 128;
    const int z = blockIdx.z;
    const float* Xb = X + (size_t)z * NPTS * DIN;
    const float* SQb = SQ + (size_t)z * NPTS;
    float* DTb = DT + (size_t)z * NPTS * NPTS;

    const int e = t & 127;

    float acc[8][8];
    #pragma unroll
    for (int i = 0; i < 8; ++i)
        #pragma unroll
        for (int j = 0; j < 8; ++j) acc[i][j] = 0.f;

    if constexpr (DIN % 32 == 0) {
        const int rh = (t >> 7) * 16;   // 0 or 16
        const float* Ar = Xb + (size_t)(i0 + e) * DIN;
        const float* Br = Xb + (size_t)(j0 + e) * DIN;
        for (int k0 = 0; k0 < DIN; k0 += 32) {
            #pragma unroll
            for (int h = 0; h < 4; ++h) {
                float4 a = *(const float4*)(Ar + k0 + rh + h * 4);
                float4 b = *(const float4*)(Br + k0 + rh + h * 4);
                As[rh + h * 4 + 0][e] = a.x; As[rh + h * 4 + 1][e] = a.y;
                As[rh + h * 4 + 2][e] = a.z; As[rh + h * 4 + 3][e] = a.w;
                Bs[rh + h * 4 + 0][e] = b.x; Bs[rh + h * 4 + 1][e] = b.y;
                Bs[rh + h * 4 + 2][e] = b.z; Bs[rh + h * 4 + 3][e] = b.w;
            }
            __syncthreads();
            #pragma unroll
            for (int r = 0; r < 32; ++r) {
                float4 a0 = *(const float4*)&As[r][ty * 4];
                float4 a1 = *(const float4*)&As[r][64 + ty * 4];
                float4 b0 = *(const float4*)&Bs[r][tx * 4];
                float4 b1 = *(const float4*)&Bs[r][64 + tx * 4];
                float av[8] = {a0.x, a0.y, a0.z, a0.w, a1.x, a1.y, a1.z, a1.w};
                float bv[8] = {b0.x, b0.y, b0.z, b0.w, b1.x, b1.y, b1.z, b1.w};
                #pragma unroll
                for (int i = 0; i < 8; ++i)
                    #pragma unroll
                    for (int j = 0; j < 8; ++j)
                        acc[i][j] = fmaf(av[i], bv[j], acc[i][j]);
            }
            __syncthreads();
        }
    } else {
        const int rh = (t >> 7) * 8;
        #pragma unroll
        for (int i = 0; i < 8; ++i) {
            int k = rh + i;
            As[rh + i][e] = (k < DIN) ? Xb[(size_t)(i0 + e) * DIN + k] : 0.f;
            Bs[rh + i][e] = (k < DIN) ? Xb[(size_t)(j0 + e) * DIN + k] : 0.f;
        }
        __syncthreads();
        #pragma unroll
        for (int r = 0; r < 16; ++r) {
            float4 a0 = *(const float4*)&As[r][ty * 4];
            float4 a1 = *(const float4*)&As[r][64 + ty * 4];
            float4 b0 = *(const float4*)&Bs[r][tx * 4];
            float4 b1 = *(const float4*)&Bs[r][64 + tx * 4];
            float av[8] = {a0.x, a0.y, a0.z, a0.w, a1.x, a1.y, a1.z, a1.w};
            float bv[8] = {b0.x, b0.y, b0.z, b0.w, b1.x, b1.y, b1.z, b1.w};
            #pragma unroll
            for (int i = 0; i < 8; ++i)
                #pragma unroll
                for (int j = 0; j < 8; ++j)
                    acc[i][j] = fmaf(av[i], bv[j], acc[i][j]);
        }
        __syncthreads();
    }

    float sqi[8], sqj[8];
    #pragma unroll
    for (int i = 0; i < 8; ++i) {
        int ro = (i < 4) ? (ty * 4 + i) : (64 + ty * 4 + (i - 4));
        sqi[i] = SQb[i0 + ro];
    }
    #pragma unroll
    for (int j = 0; j < 8; ++j) {
        int co = (j < 4) ? (tx * 4 + j) : (64 + tx * 4 + (j - 4));
        sqj[j] = SQb[j0 + co];
    }
    // forward block (i0, j0)
    #pragma unroll
    for (int i = 0; i < 8; ++i) {
        int ro = (i < 4) ? (ty * 4 + i) : (64 + ty * 4 + (i - 4));
        float* out = DTb + (size_t)(i0 + ro) * NPTS + j0;
        float4 o0, o1;
        o0.x = (sqi[i] + sqj[0]) - 2.f * acc[i][0];
        o0.y = (sqi[i] + sqj[1]) - 2.f * acc[i][1];
        o0.z = (sqi[i] + sqj[2]) - 2.f * acc[i][2];
        o0.w = (sqi[i] + sqj[3]) - 2.f * acc[i][3];
        o1.x = (sqi[i] + sqj[4]) - 2.f * acc[i][4];
        o1.y = (sqi[i] + sqj[5]) - 2.f * acc[i][5];
        o1.z = (sqi[i] + sqj[6]) - 2.f * acc[i][6];
        o1.w = (sqi[i] + sqj[7]) - 2.f * acc[i][7];
        *(float4*)(out + tx * 4) = o0;
        *(float4*)(out + 64 + tx * 4) = o1;
    }
    // mirror block (j0, i0): acc rows i=0..3 / 4..7 are consecutive output addresses
    if (bi != bj) {
        #pragma unroll
        for (int j = 0; j < 8; ++j) {
            int co = (j < 4) ? (tx * 4 + j) : (64 + tx * 4 + (j - 4));
            float* out = DTb + (size_t)(j0 + co) * NPTS + i0;
            float4 o0, o1;
            o0.x = (sqi[0] + sqj[j]) - 2.f * acc[0][j];
            o0.y = (sqi[1] + sqj[j]) - 2.f * acc[1][j];
            o0.z = (sqi[2] + sqj[j]) - 2.f * acc[2][j];
            o0.w = (sqi[3] + sqj[j]) - 2.f * acc[3][j];
            o1.x = (sqi[4] + sqj[j]) - 2.f * acc[4][j];
            o1.y = (sqi[5] + sqj[j]) - 2.f * acc[5][j];
            o1.z = (sqi[6] + sqj[j]) - 2.f * acc[6][j];
            o1.w = (sqi[7] + sqj[j]) - 2.f * acc[7][j];
            *(float4*)(out + ty * 4) = o0;
            *(float4*)(out + 64 + ty * 4) = o1;
        }
    }
}

// ---------------- knn select: one query per wave, dists in registers (R8 version) ----
__global__ __launch_bounds__(256) void knn_select_kernel(const float* __restrict__ DT,
                                                         int* __restrict__ IDX, int qoff) {
    const int t = threadIdx.x;
    const int w = t >> 6, lane = t & 63;
    const int q = blockIdx.x * 4 + w;       // half-local query
    const float* dq = DT + (size_t)q * NPTS;
    const int l4 = lane << 2;

    float vals[32];
    #pragma unroll
    for (int s = 0; s < 8; ++s) {
        float4 v = *(const float4*)(dq + s * 256 + l4);
        vals[s * 4 + 0] = v.x; vals[s * 4 + 1] = v.y;
        vals[s * 4 + 2] = v.z; vals[s * 4 + 3] = v.w;
    }
    unsigned rm = 0;
    float best = INFINITY; int bslot = 32;
    #pragma unroll
    for (int sl = 0; sl < 32; ++sl)
        if (vals[sl] < best) { best = vals[sl]; bslot = sl; }

    for (int rep = 0; rep < KNN; ++rep) {
        int bj = (bslot < 32) ? ((bslot >> 2) * 256 + l4 + (bslot & 3)) : NPTS;
        float gb = best; int gj = bj;
        #pragma unroll
        for (int off = 1; off < 64; off <<= 1) {
            float ov = __shfl_xor(gb, off);
            int oj = __shfl_xor(gj, off);
            if (ov < gb || (ov == gb && oj < gj)) { gb = ov; gj = oj; }
        }
        if (lane == 0) IDX[(size_t)(qoff + q) * KNN + rep] = gj;
        if (((gj >> 2) & 63) == lane) {
            int slot = ((gj >> 8) << 2) | (gj & 3);
            rm |= (1u << slot);
            best = INFINITY; bslot = 32;
            #pragma unroll
            for (int sl = 0; sl < 32; ++sl)
                if (!(rm & (1u << sl)) && vals[sl] < best) { best = vals[sl]; bslot = sl; }
        }
    }
}

// ---------------- gemm big: C[M,N] = A[M,K]@B[K,N] + bias, 128x128, BK=32, plain -----
template <int KK, int NN>
__global__ __launch_bounds__(256) void gemm_big_kernel(const float* __restrict__ A,
                                                       const float* __restrict__ B,
                                                       const float* __restrict__ bias,
                                                       float* __restrict__ C) {
    __shared__ float As[32][132];
    __shared__ float Bs[32][132];
    const int t = threadIdx.x;
    const int tx = t & 15, ty = t >> 4;
    const int m0 = blockIdx.x * 128;
    const int c0 = blockIdx.y * 128;

    float acc[8][8];
    #pragma unroll
    for (int i = 0; i < 8; ++i)
        #pragma unroll
        for (int j = 0; j < 8; ++j) acc[i][j] = 0.f;

    const int e = t & 127;
    const int rh = (t >> 7) * 16;   // 0 or 16
    const float* Ar = A + (size_t)(m0 + e) * KK + rh;
    const int br = t & 31;
    const int bc = (t >> 5) * 16;
    const float* Wbase = B + (size_t)br * NN + c0 + bc;

    for (int k0 = 0; k0 < KK; k0 += 32) {
        #pragma unroll
        for (int h = 0; h < 4; ++h) {
            float4 a = *(const float4*)(Ar + k0 + h * 4);
            As[rh + h * 4 + 0][e] = a.x; As[rh + h * 4 + 1][e] = a.y;
            As[rh + h * 4 + 2][e] = a.z; As[rh + h * 4 + 3][e] = a.w;
            *(float4*)&Bs[br][bc + h * 4] = *(const float4*)(Wbase + (size_t)k0 * NN + h * 4);
        }
        __syncthreads();
        #pragma unroll
        for (int r = 0; r < 32; ++r) {
            float4 a0 = *(const float4*)&As[r][ty * 4];
            float4 a1 = *(const float4*)&As[r][64 + ty * 4];
            float4 b0 = *(const float4*)&Bs[r][tx * 4];
            float4 b1 = *(const float4*)&Bs[r][64 + tx * 4];
            float av[8] = {a0.x, a0.y, a0.z, a0.w, a1.x, a1.y, a1.z, a1.w};
            float bv[8] = {b0.x, b0.y, b0.z, b0.w, b1.x, b1.y, b1.z, b1.w};
            #pragma unroll
            for (int i = 0; i < 8; ++i)
                #pragma unroll
                for (int j = 0; j < 8; ++j)
                    acc[i][j] = fmaf(av[i], bv[j], acc[i][j]);
        }
        __syncthreads();
    }

    float bvv[8];
    #pragma unroll
    for (int j = 0; j < 8; ++j) {
        int co = (j < 4) ? (tx * 4 + j) : (64 + tx * 4 + (j - 4));
        bvv[j] = bias[c0 + co];
    }
    #pragma unroll
    for (int i = 0; i < 8; ++i) {
        int ro = (i < 4) ? (ty * 4 + i) : (64 + ty * 4 + (i - 4));
        float* out = C + (size_t)(m0 + ro) * NN + c0;
        float4 o0, o1;
        o0.x = acc[i][0] + bvv[0]; o0.y = acc[i][1] + bvv[1];
        o0.z = acc[i][2] + bvv[2]; o0.w = acc[i][3] + bvv[3];
        o1.x = acc[i][4] + bvv[4]; o1.y = acc[i][5] + bvv[5];
        o1.z = acc[i][6] + bvv[6]; o1.w = acc[i][7] + bvv[7];
        *(float4*)(out + tx * 4) = o0;
        *(float4*)(out + 64 + tx * 4) = o1;
    }
}

// ---------------- generic tiled GEMM (fallback, 64x64): C = A@B + bias ----------------
template <int KK, int NN>
__global__ __launch_bounds__(256) void gemm_pq_kernel(const float* __restrict__ A,
                                                      const float* __restrict__ B,
                                                      const float* __restrict__ bias,
                                                      float* __restrict__ C) {
    __shared__ float As[16][68];
    __shared__ float Bs[16][64];
    const int t = threadIdx.x;
    const int tx = t & 15, ty = t >> 4;
    const int m0 = blockIdx.x * 64;
    const int c0 = blockIdx.y * 64;
    float acc[4][4];
    #pragma unroll
    for (int i = 0; i < 4; ++i)
        #pragma unroll
        for (int j = 0; j < 4; ++j) acc[i][j] = 0.f;

    constexpr int KCH = (KK + 15) / 16;
    for (int kc = 0; kc < KCH; ++kc) {
        const int k0 = kc * 16;
        {
            int m = t & 63;
            int r4 = (t >> 6) * 4;
            if constexpr (KK % 16 == 0) {
                float4 v = *(const float4*)(A + (size_t)(m0 + m) * KK + k0 + r4);
                As[r4 + 0][m] = v.x; As[r4 + 1][m] = v.y;
                As[r4 + 2][m] = v.z; As[r4 + 3][m] = v.w;
            } else {
                #pragma unroll
                for (int i = 0; i < 4; ++i) {
                    int r = r4 + i;
                    As[r][m] = (k0 + r < KK) ? A[(size_t)(m0 + m) * KK + k0 + r] : 0.f;
                }
            }
        }
        {
            int r = t >> 4;
            int c = (t & 15) * 4;
            float4 v = make_float4(0.f, 0.f, 0.f, 0.f);
            if (k0 + r < KK) v = *(const float4*)(B + (size_t)(k0 + r) * NN + c0 + c);
            *(float4*)&Bs[r][c] = v;
        }
        __syncthreads();
        #pragma unroll
        for (int r = 0; r < 16; ++r) {
            float4 a4 = *(const float4*)&As[r][ty * 4];
            float4 b4 = *(const float4*)&Bs[r][tx * 4];
            float av[4] = {a4.x, a4.y, a4.z, a4.w};
            float bv[4] = {b4.x, b4.y, b4.z, b4.w};
            #pragma unroll
            for (int i = 0; i < 4; ++i)
                #pragma unroll
                for (int j = 0; j < 4; ++j)
                    acc[i][j] = fmaf(av[i], bv[j], acc[i][j]);
        }
        __syncthreads();
    }
    float4 bv4 = *(const float4*)(bias + c0 + tx * 4);
    float bv[4] = {bv4.x, bv4.y, bv4.z, bv4.w};
    #pragma unroll
    for (int i = 0; i < 4; ++i) {
        float4 o;
        o.x = acc[i][0] + bv[0];
        o.y = acc[i][1] + bv[1];
        o.z = acc[i][2] + bv[2];
        o.w = acc[i][3] + bv[3];
        *(float4*)(C + (size_t)(m0 + ty * 4 + i) * NN + c0 + tx * 4) = o;
    }
}

// ---------------- edge small (DOUT<=32): 64 edges x 64 cols, 4x4/thread (R8) ----------
template <int D2, int DOUT>
__global__ __launch_bounds__(256) void edge_kernel(const float* __restrict__ PQ,
                                                   const int* __restrict__ IDX,
                                                   const float* __restrict__ W2,
                                                   const float* __restrict__ b2,
                                                   float* __restrict__ Xn) {
    constexpr int N4 = 2 * D2;
    __shared__ float As[16][68];
    __shared__ float Bs[16][64];
    __shared__ int gjs[64];
    const int t = threadIdx.x;
    const int tx = t & 15, ty = t >> 4;
    const int nb = blockIdx.x * 4;
    const int c0 = blockIdx.y * 64;

    if (t < 64) {
        int node = nb + (t >> 4);
        int bstart = (node / NPTS) * NPTS;
        gjs[t] = bstart + IDX[(size_t)node * KNN + (t & 15)];
    }
    __syncthreads();

    float acc[4][4];
    #pragma unroll
    for (int i = 0; i < 4; ++i)
        #pragma unroll
        for (int j = 0; j < 4; ++j) acc[i][j] = 0.f;

    const int e = t & 63;
    const int r4 = (t >> 6) * 4;
    const int gi = nb + (e >> 4);

    for (int k0 = 0; k0 < D2; k0 += 16) {
        {
            int gj = gjs[e];
            float4 p = *(const float4*)(PQ + (size_t)gi * N4 + k0 + r4);
            float4 q = *(const float4*)(PQ + (size_t)gj * N4 + D2 + k0 + r4);
            As[r4 + 0][e] = fmaxf(p.x + q.x, 0.f);
            As[r4 + 1][e] = fmaxf(p.y + q.y, 0.f);
            As[r4 + 2][e] = fmaxf(p.z + q.z, 0.f);
            As[r4 + 3][e] = fmaxf(p.w + q.w, 0.f);
        }
        {
            int r = t >> 4;
            int c = (t & 15) * 4;
            float4 v = make_float4(0.f, 0.f, 0.f, 0.f);
            if (c0 + c < DOUT) v = *(const float4*)(W2 + (size_t)(k0 + r) * DOUT + c0 + c);
            *(float4*)&Bs[r][c] = v;
        }
        __syncthreads();
        #pragma unroll
        for (int r = 0; r < 16; ++r) {
            float4 a4 = *(const float4*)&As[r][ty * 4];
            float4 b4 = *(const float4*)&Bs[r][tx * 4];
            float av[4] = {a4.x, a4.y, a4.z, a4.w};
            float bv[4] = {b4.x, b4.y, b4.z, b4.w};
            #pragma unroll
            for (int i = 0; i < 4; ++i)
                #pragma unroll
                for (int j = 0; j < 4; ++j)
                    acc[i][j] = fmaf(av[i], bv[j], acc[i][j]);
        }
        __syncthreads();
    }

    float bv[4];
    #pragma unroll
    for (int j = 0; j < 4; ++j) {
        int c = c0 + tx * 4 + j;
        bv[j] = (c < DOUT) ? b2[c] : 0.f;
    }
    float s[4];
    #pragma unroll
    for (int j = 0; j < 4; ++j) {
        float ss = 0.f;
        #pragma unroll
        for (int i = 0; i < 4; ++i) ss += fmaxf(acc[i][j] + bv[j], 0.f);
        s[j] = ss;
    }
    #pragma unroll
    for (int j = 0; j < 4; ++j) Bs[ty][tx * 4 + j] = s[j];
    __syncthreads();
    if ((ty & 3) == 0) {
        int node = nb + (ty >> 2);
        #pragma unroll
        for (int j = 0; j < 4; ++j) {
            int c = c0 + tx * 4 + j;
            if (c < DOUT) {
                int cc = tx * 4 + j;
                float tot = Bs[ty][cc] + Bs[ty + 1][cc] + Bs[ty + 2][cc] + Bs[ty + 3][cc];
                Xn[(size_t)node * DOUT + c] = tot * (1.f / 16.f);
            }
        }
    }
}

// ---------------- edge mid (DOUT==64): 128 edges x 64 cols, 8x4/thread, BK=32 --------
template <int D2, int DOUT>
__global__ __launch_bounds__(256) void edge_mid_kernel(const float* __restrict__ PQ,
                                                       const int* __restrict__ IDX,
                                                       const float* __restrict__ W2,
                                                       const float* __restrict__ b2,
                                                       float* __restrict__ Xn) {
    constexpr int N4 = 2 * D2;
    __shared__ float As[32][132];
    __shared__ float Bs[32][68];
    __shared__ int gjs[128];
    const int t = threadIdx.x;
    const int tx = t & 15, ty = t >> 4;
    const int nb8 = blockIdx.x * 8;

    if (t < 128) {
        int node = nb8 + (t >> 4);
        int bstart = (node / NPTS) * NPTS;
        gjs[t] = bstart + IDX[(size_t)node * KNN + (t & 15)];
    }
    __syncthreads();

    float acc[8][4];
    #pragma unroll
    for (int i = 0; i < 8; ++i)
        #pragma unroll
        for (int j = 0; j < 4; ++j) acc[i][j] = 0.f;

    const int e = t & 127;
    const int rh = (t >> 7) * 16;   // 0 or 16
    const int gi = nb8 + (e >> 4);
    const int gj = gjs[e];
    const float* Prow = PQ + (size_t)gi * N4;
    const float* Qrow = PQ + (size_t)gj * N4 + D2;
    const int br = t & 31;
    const int bc = (t >> 5) * 8;
    const float* Wbase = W2 + (size_t)br * DOUT + bc;

    for (int k0 = 0; k0 < D2; k0 += 32) {
        #pragma unroll
        for (int h = 0; h < 4; ++h) {
            float4 p = *(const float4*)(Prow + k0 + rh + h * 4);
            float4 q = *(const float4*)(Qrow + k0 + rh + h * 4);
            As[rh + h * 4 + 0][e] = fmaxf(p.x + q.x, 0.f);
            As[rh + h * 4 + 1][e] = fmaxf(p.y + q.y, 0.f);
            As[rh + h * 4 + 2][e] = fmaxf(p.z + q.z, 0.f);
            As[rh + h * 4 + 3][e] = fmaxf(p.w + q.w, 0.f);
        }
        {
            const float* wp = Wbase + (size_t)k0 * DOUT;
            *(float4*)&Bs[br][bc] = *(const float4*)(wp);
            *(float4*)&Bs[br][bc + 4] = *(const float4*)(wp + 4);
        }
        __syncthreads();
        #pragma unroll
        for (int r = 0; r < 32; ++r) {
            float4 a0 = *(const float4*)&As[r][ty * 4];
            float4 a1 = *(const float4*)&As[r][64 + ty * 4];
            float4 b0 = *(const float4*)&Bs[r][tx * 4];
            float av[8] = {a0.x, a0.y, a0.z, a0.w, a1.x, a1.y, a1.z, a1.w};
            float bv[4] = {b0.x, b0.y, b0.z, b0.w};
            #pragma unroll
            for (int i = 0; i < 8; ++i)
                #pragma unroll
                for (int j = 0; j < 4; ++j)
                    acc[i][j] = fmaf(av[i], bv[j], acc[i][j]);
        }
        __syncthreads();
    }

    #pragma unroll
    for (int j = 0; j < 4; ++j) {
        int cl = tx * 4 + j;
        float bb = b2[cl];
        float s0 = 0.f, s1 = 0.f;
        #pragma unroll
        for (int i = 0; i < 4; ++i) {
            s0 += fmaxf(acc[i][j] + bb, 0.f);
            s1 += fmaxf(acc[4 + i][j] + bb, 0.f);
        }
        As[ty][cl] = s0;       // nodes 0..3 partials
        Bs[ty][cl] = s1;       // nodes 4..7 partials
    }
    __syncthreads();
    if (t < 128) {
        int node = t >> 4;             // 0..7
        int colb = (t & 15) * 4;
        int tg = (node & 3) * 4;
        float v0, v1, v2, v3;
        if (node < 4) {
            v0 = As[tg + 0][colb + 0] + As[tg + 1][colb + 0] + As[tg + 2][colb + 0] + As[tg + 3][colb + 0];
            v1 = As[tg + 0][colb + 1] + As[tg + 1][colb + 1] + As[tg + 2][colb + 1] + As[tg + 3][colb + 1];
            v2 = As[tg + 0][colb + 2] + As[tg + 1][colb + 2] + As[tg + 2][colb + 2] + As[tg + 3][colb + 2];
            v3 = As[tg + 0][colb + 3] + As[tg + 1][colb + 3] + As[tg + 2][colb + 3] + As[tg + 3][colb + 3];
        } else {
            v0 = Bs[tg + 0][colb + 0] + Bs[tg + 1][colb + 0] + Bs[tg + 2][colb + 0] + Bs[tg + 3][colb + 0];
            v1 = Bs[tg + 0][colb + 1] + Bs[tg + 1][colb + 1] + Bs[tg + 2][colb + 1] + Bs[tg + 3][colb + 1];
            v2 = Bs[tg + 0][colb + 2] + Bs[tg + 1][colb + 2] + Bs[tg + 2][colb + 2] + Bs[tg + 3][colb + 2];
            v3 = Bs[tg + 0][colb + 3] + Bs[tg + 1][colb + 3] + Bs[tg + 2][colb + 3] + Bs[tg + 3][colb + 3];
        }
        float4 o;
        o.x = v0 * (1.f / 16.f); o.y = v1 * (1.f / 16.f);
        o.z = v2 * (1.f / 16.f); o.w = v3 * (1.f / 16.f);
        *(float4*)(Xn + (size_t)(nb8 + node) * DOUT + colb) = o;
    }
}

// ---------------- edge big (DOUT>=128): 128x128, 8x8/thread, BK=32, plain ------------
template <int D2, int DOUT>
__global__ __launch_bounds__(256) void edge_big_kernel(const float* __restrict__ PQ,
                                                       const int* __restrict__ IDX,
                                                       const float* __restrict__ W2,
                                                       const float* __restrict__ b2,
                                                       float* __restrict__ Xn) {
    constexpr int N4 = 2 * D2;
    __shared__ float As[32][132];
    __shared__ float Bs[32][132];
    __shared__ int gjs[128];
    const int t = threadIdx.x;
    const int tx = t & 15, ty = t >> 4;
    const int nb8 = blockIdx.x * 8;
    const int c0 = blockIdx.y * 128;

    if (t < 128) {
        int node = nb8 + (t >> 4);
        int bstart = (node / NPTS) * NPTS;
        gjs[t] = bstart + IDX[(size_t)node * KNN + (t & 15)];
    }
    __syncthreads();

    float acc[8][8];
    #pragma unroll
    for (int i = 0; i < 8; ++i)
        #pragma unroll
        for (int j = 0; j < 8; ++j) acc[i][j] = 0.f;

    const int e = t & 127;
    const int rh = (t >> 7) * 16;   // 0 or 16
    const int gi = nb8 + (e >> 4);
    const int gj = gjs[e];
    const float* Prow = PQ + (size_t)gi * N4;
    const float* Qrow = PQ + (size_t)gj * N4 + D2;
    const int br = t & 31;
    const int bc = (t >> 5) * 16;
    const float* Wbase = W2 + (size_t)br * DOUT + c0 + bc;

    for (int k0 = 0; k0 < D2; k0 += 32) {
        #pragma unroll
        for (int h = 0; h < 4; ++h) {
            float4 p = *(const float4*)(Prow + k0 + rh + h * 4);
            float4 q = *(const float4*)(Qrow + k0 + rh + h * 4);
            As[rh + h * 4 + 0][e] = fmaxf(p.x + q.x, 0.f);
            As[rh + h * 4 + 1][e] = fmaxf(p.y + q.y, 0.f);
            As[rh + h * 4 + 2][e] = fmaxf(p.z + q.z, 0.f);
            As[rh + h * 4 + 3][e] = fmaxf(p.w + q.w, 0.f);
        }
        {
            const float* wp = Wbase + (size_t)k0 * DOUT;
            #pragma unroll
            for (int h = 0; h < 4; ++h)
                *(float4*)&Bs[br][bc + h * 4] = *(const float4*)(wp + h * 4);
        }
        __syncthreads();
        #pragma unroll
        for (int r = 0; r < 32; ++r) {
            float4 a0 = *(const float4*)&As[r][ty * 4];
            float4 a1 = *(const float4*)&As[r][64 + ty * 4];
            float4 b0 = *(const float4*)&Bs[r][tx * 4];
            float4 b1 = *(const float4*)&Bs[r][64 + tx * 4];
            float av[8] = {a0.x, a0.y, a0.z, a0.w, a1.x, a1.y, a1.z, a1.w};
            float bv[8] = {b0.x, b0.y, b0.z, b0.w, b1.x, b1.y, b1.z, b1.w};
            #pragma unroll
            for (int i = 0; i < 8; ++i)
                #pragma unroll
                for (int j = 0; j < 8; ++j)
                    acc[i][j] = fmaf(av[i], bv[j], acc[i][j]);
        }
        __syncthreads();
    }

    #pragma unroll
    for (int j = 0; j < 8; ++j) {
        int cl = (j < 4) ? (tx * 4 + j) : (64 + tx * 4 + (j - 4));
        float bb = b2[c0 + cl];
        float s0 = 0.f, s1 = 0.f;
        #pragma unroll
        for (int i = 0; i < 4; ++i) {
            s0 += fmaxf(acc[i][j] + bb, 0.f);
            s1 += fmaxf(acc[4 + i][j] + bb, 0.f);
        }
        As[ty][cl] = s0;
        Bs[ty][cl] = s1;
    }
    __syncthreads();
    {
        int node = t >> 5;
        int colb = (t * 4) & 127;
        int tg = (node & 3) * 4;
        float4 o;
        float v0, v1, v2, v3;
        if (node < 4) {
            v0 = As[tg + 0][colb + 0] + As[tg + 1][colb + 0] + As[tg + 2][colb + 0] + As[tg + 3][colb + 0];
            v1 = As[tg + 0][colb + 1] + As[tg + 1][colb + 1] + As[tg + 2][colb + 1] + As[tg + 3][colb + 1];
            v2 = As[tg + 0][colb + 2] + As[tg + 1][colb + 2] + As[tg + 2][colb + 2] + As[tg + 3][colb + 2];
            v3 = As[tg + 0][colb + 3] + As[tg + 1][colb + 3] + As[tg + 2][colb + 3] + As[tg + 3][colb + 3];
        } else {
            v0 = Bs[tg + 0][colb + 0] + Bs[tg + 1][colb + 0] + Bs[tg + 2][colb + 0] + Bs[tg + 3][colb + 0];
            v1 = Bs[tg + 0][colb + 1] + Bs[tg + 1][colb + 1] + Bs[tg + 2][colb + 1] + Bs[tg + 3][colb + 1];
            v2 = Bs[tg + 0][colb + 2] + Bs[tg + 1][colb + 2] + Bs[tg + 2][colb + 2] + Bs[tg + 3][colb + 2];
            v3 = Bs[tg + 0][colb + 3] + Bs[tg + 1][colb + 3] + Bs[tg + 2][colb + 3] + Bs[tg + 3][colb + 3];
        }
        o.x = v0 * (1.f / 16.f); o.y = v1 * (1.f / 16.f);
        o.z = v2 * (1.f / 16.f); o.w = v3 * (1.f / 16.f);
        *(float4*)(Xn + (size_t)(nb8 + node) * DOUT + c0 + colb) = o;
    }
}

// ---------------- final: mean over nodes + 16x2 projection ----------------
__global__ __launch_bounds__(256) void final_kernel(const float* __restrict__ X,
                                                    const float* __restrict__ Wf,
                                                    const float* __restrict__ bfin,
                                                    float* __restrict__ out) {
    __shared__ float red[16][17];
    __shared__ float pool[16];
    const int b = blockIdx.x;
    const int t = threadIdx.x;
    const int c = t & 15, rg = t >> 4;
    float s = 0.f;
    for (int n = rg; n < NPTS; n += 16) s += X[(size_t)(b * NPTS + n) * 16 + c];
    red[rg][c] = s;
    __syncthreads();
    if (t < 16) {
        float tot = 0.f;
        #pragma unroll
        for (int i = 0; i < 16; ++i) tot += red[i][t];
        pool[t] = tot * (1.f / NPTS);
    }
    __syncthreads();
    if (t < 2) {
        float a = bfin[t];
        #pragma unroll
        for (int cc = 0; cc < 16; ++cc) a = fmaf(pool[cc], Wf[cc * 2 + t], a);
        out[b * 2 + t] = a;
    }
}

// ---------------- per-layer driver ----------------
template <int DIN, int DOUT>
static void run_layer(const float* Xin, float* Xout, float* PQ, float* SQ, int* IDX,
                      float* WCAT, float* BCAT,
                      const float* W1, const float* b1, const float* W2, const float* b2,
                      hipStream_t stream) {
    constexpr int D2 = 2 * DOUT;
    constexpr int N4 = 2 * D2;
    int prep_blocks = (DIN * N4 + 255) / 256;
    sqprep_kernel<<<BN / 256 + prep_blocks, 256, 0, stream>>>(Xin, SQ, W1, b1, WCAT, BCAT, DIN, D2);
    for (int h = 0; h < 2; ++h) {
        dim3 gg(136, 1, 4);   // triangular tile pairs
        gram_kernel<DIN><<<gg, 256, 0, stream>>>(Xin + (size_t)h * 4 * NPTS * DIN,
                                                 SQ + (size_t)h * 4 * NPTS, PQ);
        knn_select_kernel<<<2048, 256, 0, stream>>>(PQ, IDX, h * 8192);
    }
    if constexpr (N4 % 128 == 0 && DIN % 32 == 0) {
        dim3 g1(BN / 128, N4 / 128);
        gemm_big_kernel<DIN, N4><<<g1, 256, 0, stream>>>(Xin, WCAT, BCAT, PQ);
    } else {
        dim3 g1(BN / 64, N4 / 64);
        gemm_pq_kernel<DIN, N4><<<g1, 256, 0, stream>>>(Xin, WCAT, BCAT, PQ);
    }
    if constexpr (DOUT >= 128) {
        dim3 g2(BN / 8, DOUT / 128);
        edge_big_kernel<D2, DOUT><<<g2, 256, 0, stream>>>(PQ, IDX, W2, b2, Xout);
    } else if constexpr (DOUT == 64) {
        dim3 g2(BN / 8, 1);
        edge_mid_kernel<D2, DOUT><<<g2, 256, 0, stream>>>(PQ, IDX, W2, b2, Xout);
    } else {
        dim3 g2(BN / 4, (DOUT + 63) / 64);
        edge_kernel<D2, DOUT><<<g2, 256, 0, stream>>>(PQ, IDX, W2, b2, Xout);
    }
}

extern "C" void kernel_launch(void* const* d_in, const int* in_sizes, int n_in,
                              void* d_out, int out_size, void* d_ws, size_t ws_size,
                              hipStream_t stream) {
    (void)in_sizes; (void)n_in; (void)out_size; (void)ws_size;
    const float* x = (const float*)d_in[0];
    const float* W1a[6]; const float* b1a[6]; const float* W2a[6]; const float* b2a[6];
    for (int l = 0; l < 6; ++l) {
        W1a[l] = (const float*)d_in[1 + 4 * l];
        b1a[l] = (const float*)d_in[2 + 4 * l];
        W2a[l] = (const float*)d_in[3 + 4 * l];
        b2a[l] = (const float*)d_in[4 + 4 * l];
    }
    const float* Wf = (const float*)d_in[25];
    const float* bfin = (const float*)d_in[26];

    float* ws = (float*)d_ws;
    float* X0   = ws;                                   // 16384*256
    float* X1   = X0 + (size_t)BN * 256;                // 16384*256
    float* PQ   = X1 + (size_t)BN * 256;                // 16384*1024 (also knn DT: 8192*2048)
    float* SQ   = PQ + (size_t)BN * 1024;               // 16384
    int*   IDX  = (int*)(SQ + BN);                      // 16384*16
    float* WCAT = (float*)(IDX + (size_t)BN * KNN);     // 131072
    float* BCAT = WCAT + 131072;                        // 1024

    run_layer<3,   32>(x,  X0, PQ, SQ, IDX, WCAT, BCAT, W1a[0], b1a[0], W2a[0], b2a[0], stream);
    run_layer<32, 128>(X0, X1, PQ, SQ, IDX, WCAT, BCAT, W1a[1], b1a[1], W2a[1], b2a[1], stream);
    run_layer<128,256>(X1, X0, PQ, SQ, IDX, WCAT, BCAT, W1a[2], b1a[2], W2a[2], b2a[2], stream);
    run_layer<256, 64>(X0, X1, PQ, SQ, IDX, WCAT, BCAT, W1a[3], b1a[3], W2a[3], b2a[3], stream);
    run_layer<64,  32>(X1, X0, PQ, SQ, IDX, WCAT, BCAT, W1a[4], b1a[4], W2a[4], b2a[4], stream);
    run_layer<32,  16>(X0, X1, PQ, SQ, IDX, WCAT, BCAT, W1a[5], b1a[5], W2a[5], b2a[5], stream);
    final_kernel<<<NB, 256, 0, stream>>>(X1, Wf, bfin, (float*)d_out);
}